// Round 1
// baseline (409.752 us; speedup 1.0000x reference)
//
#include <hip/hip_runtime.h>
#include <stdint.h>

#define N_ANCH 8192
#define DIM 1024
#define NTHREADS 256

// ---------------------------------------------------------------------------
// Threefry-2x32 with key = jax.random.key(42) => (k0,k1) = (0, 42).
// Returns o0 ^ o1 (JAX partitionable mode, bit_width<=32 combine).
// ---------------------------------------------------------------------------
__device__ __forceinline__ uint32_t rotl32(uint32_t x, int r) {
  return (x << r) | (x >> (32 - r));
}

__device__ __forceinline__ uint32_t tf_bits(uint32_t hi, uint32_t lo) {
  const uint32_t ks0 = 0u;
  const uint32_t ks1 = 42u;
  const uint32_t ks2 = 0u ^ 42u ^ 0x1BD11BDAu;
  uint32_t x0 = hi + ks0;
  uint32_t x1 = lo + ks1;
#define R1(r) x0 += x1; x1 = rotl32(x1, r); x1 ^= x0;
#define R4(a,b,c,d) R1(a) R1(b) R1(c) R1(d)
  R4(13, 15, 26, 6)   x0 += ks1; x1 += ks2 + 1u;
  R4(17, 29, 16, 24)  x0 += ks2; x1 += ks0 + 2u;
  R4(13, 15, 26, 6)   x0 += ks0; x1 += ks1 + 3u;
  R4(17, 29, 16, 24)  x0 += ks1; x1 += ks2 + 4u;
  R4(13, 15, 26, 6)   x0 += ks2; x1 += ks0 + 5u;
#undef R4
#undef R1
  return x0 ^ x1;
}

__device__ __forceinline__ unsigned long long shfl_down_u64(unsigned long long v, int off) {
  unsigned int lo = (unsigned int)v;
  unsigned int hi = (unsigned int)(v >> 32);
  lo = __shfl_down(lo, off, 64);
  hi = __shfl_down(hi, off, 64);
  return ((unsigned long long)hi << 32) | (unsigned long long)lo;
}

// ---------------------------------------------------------------------------
// Kernel 1: per-anchor masked Gumbel argmax (pos & neg) over all 8192 columns.
// Ordering by (bits>>9) is exactly monotone with the JAX gumbel values near
// the max; ties in (bits>>9) are exact ties in JAX -> first index wins.
// Packed key = ((rank+1) << 13) | (8191 - j): u64 max == argmax w/ first-idx
// tie-break. rank 0 (packed high part 0) == "no candidate".
// ---------------------------------------------------------------------------
__global__ __launch_bounds__(NTHREADS) void select_kernel(
    const int* __restrict__ cat, int* __restrict__ posIdx, int* __restrict__ negIdx) {
  __shared__ int scat[N_ANCH];
  __shared__ unsigned long long red[2][4];
  const int t = threadIdx.x;
  for (int j = t; j < N_ANCH; j += NTHREADS) scat[j] = cat[j];
  __syncthreads();

  const int i = blockIdx.x;
  const int ci = scat[i];

  uint32_t bpR = 0u; int bpJ = 0;
  uint32_t bnR = 0u; int bnJ = 0;
  const uint32_t base = (uint32_t)i << 13;  // i * 8192, flat = i*N + j < 2^26

  for (int j = t; j < N_ANCH; j += NTHREADS) {
    const uint32_t bits = tf_bits(0u, base + (uint32_t)j);  // counts_hi = 0
    const uint32_t r = (bits >> 9) + 1u;                    // +1 so 0 = invalid
    const int cj = scat[j];
    const bool eq = (cj == ci);
    const uint32_t rp = (eq && (j != i)) ? r : 0u;
    const uint32_t rn = eq ? 0u : r;
    if (rp > bpR) { bpR = rp; bpJ = j; }  // strict > keeps earliest j per thread
    if (rn > bnR) { bnR = rn; bnJ = j; }
  }

  unsigned long long kp = ((unsigned long long)bpR << 13) |
                          (unsigned long long)(N_ANCH - 1 - bpJ);
  unsigned long long kn = ((unsigned long long)bnR << 13) |
                          (unsigned long long)(N_ANCH - 1 - bnJ);

  for (int off = 32; off > 0; off >>= 1) {
    unsigned long long op = shfl_down_u64(kp, off);
    unsigned long long on = shfl_down_u64(kn, off);
    if (op > kp) kp = op;
    if (on > kn) kn = on;
  }
  const int wave = t >> 6;
  if ((t & 63) == 0) { red[0][wave] = kp; red[1][wave] = kn; }
  __syncthreads();
  if (t == 0) {
    kp = red[0][0]; kn = red[1][0];
    #pragma unroll
    for (int w = 1; w < 4; ++w) {
      if (red[0][w] > kp) kp = red[0][w];
      if (red[1][w] > kn) kn = red[1][w];
    }
    posIdx[i] = (kp >> 13) ? (N_ANCH - 1 - (int)(kp & 8191ull)) : -1;
    negIdx[i] = (kn >> 13) ? (N_ANCH - 1 - (int)(kn & 8191ull)) : -1;
  }
}

// ---------------------------------------------------------------------------
// Kernel 2: one wave per anchor; pos/neg L2 distances + triplet accumulate.
// ---------------------------------------------------------------------------
__global__ __launch_bounds__(256) void loss_kernel(
    const float* __restrict__ eeg, const float* __restrict__ text,
    const int* __restrict__ posIdx, const int* __restrict__ negIdx,
    float* __restrict__ acc) {
  const int lane = threadIdx.x & 63;
  const int wave = threadIdx.x >> 6;
  const int i = (blockIdx.x << 2) + wave;
  const int p = posIdx[i];
  const int n = negIdx[i];
  if ((p | n) < 0) return;  // invalid anchor (wave-uniform branch)

  const float4* ea = reinterpret_cast<const float4*>(eeg) + (size_t)i * (DIM / 4);
  const float4* tp = reinterpret_cast<const float4*>(text) + (size_t)p * (DIM / 4);
  const float4* tn = reinterpret_cast<const float4*>(text) + (size_t)n * (DIM / 4);

  float sp = 0.f, sn = 0.f;
  #pragma unroll
  for (int k = lane; k < DIM / 4; k += 64) {
    const float4 a = ea[k];
    const float4 b = tp[k];
    const float4 c = tn[k];
    float d0 = a.x - b.x + 1e-6f, d1 = a.y - b.y + 1e-6f;
    float d2 = a.z - b.z + 1e-6f, d3 = a.w - b.w + 1e-6f;
    sp += d0 * d0 + d1 * d1 + d2 * d2 + d3 * d3;
    d0 = a.x - c.x + 1e-6f; d1 = a.y - c.y + 1e-6f;
    d2 = a.z - c.z + 1e-6f; d3 = a.w - c.w + 1e-6f;
    sn += d0 * d0 + d1 * d1 + d2 * d2 + d3 * d3;
  }
  for (int off = 32; off > 0; off >>= 1) {
    sp += __shfl_down(sp, off, 64);
    sn += __shfl_down(sn, off, 64);
  }
  if (lane == 0) {
    float per = sqrtf(sp) - sqrtf(sn) + 0.2f;
    per = per > 0.f ? per : 0.f;
    atomicAdd(&acc[0], per);
    atomicAdd(&acc[1], 1.0f);
  }
}

__global__ void init_kernel(float* __restrict__ acc) {
  if (threadIdx.x < 2) acc[threadIdx.x] = 0.f;
}

__global__ void final_kernel(const float* __restrict__ acc, float* __restrict__ out) {
  out[0] = (acc[1] > 0.f) ? acc[0] / acc[1] : 0.f;
}

extern "C" void kernel_launch(void* const* d_in, const int* in_sizes, int n_in,
                              void* d_out, int out_size, void* d_ws, size_t ws_size,
                              hipStream_t stream) {
  const float* eeg  = (const float*)d_in[0];
  const float* text = (const float*)d_in[1];
  const int*   cat  = (const int*)d_in[2];
  float* out = (float*)d_out;

  int* posIdx = (int*)d_ws;
  int* negIdx = posIdx + N_ANCH;
  float* acc  = (float*)(negIdx + N_ANCH);

  hipLaunchKernelGGL(init_kernel, dim3(1), dim3(64), 0, stream, acc);
  hipLaunchKernelGGL(select_kernel, dim3(N_ANCH), dim3(NTHREADS), 0, stream,
                     cat, posIdx, negIdx);
  hipLaunchKernelGGL(loss_kernel, dim3(N_ANCH / 4), dim3(256), 0, stream,
                     eeg, text, posIdx, negIdx, acc);
  hipLaunchKernelGGL(final_kernel, dim3(1), dim3(1), 0, stream, acc, out);
}

// Round 2
// 150.020 us; speedup vs baseline: 2.7313x; 2.7313x over previous
//
#include <hip/hip_runtime.h>
#include <stdint.h>

#define N_ANCH 8192
#define DIM 1024
#define NT 256

// ---------------------------------------------------------------------------
// Threefry-2x32, key = jax.random.key(42) => (0, 42); counts hi = 0 always
// (flat index i*8192+j < 2^26). Returns o0 ^ o1 (JAX partitionable combine).
// Validated bit-exact vs JAX in round 1 (absmax 0.0).
// ---------------------------------------------------------------------------
__device__ __forceinline__ uint32_t rotl32(uint32_t x, int r) {
  return (x << r) | (x >> (32 - r));
}

__device__ __forceinline__ uint32_t tf_bits(uint32_t lo) {
  const uint32_t ks0 = 0u;
  const uint32_t ks1 = 42u;
  const uint32_t ks2 = 42u ^ 0x1BD11BDAu;
  uint32_t x0 = 0u + ks0;
  uint32_t x1 = lo + ks1;
#define R1(r) x0 += x1; x1 = rotl32(x1, r); x1 ^= x0;
#define R4(a,b,c,d) R1(a) R1(b) R1(c) R1(d)
  R4(13, 15, 26, 6)   x0 += ks1; x1 += ks2 + 1u;
  R4(17, 29, 16, 24)  x0 += ks2; x1 += ks0 + 2u;
  R4(13, 15, 26, 6)   x0 += ks0; x1 += ks1 + 3u;
  R4(17, 29, 16, 24)  x0 += ks1; x1 += ks2 + 4u;
  R4(13, 15, 26, 6)   x0 += ks2; x1 += ks0 + 5u;
#undef R4
#undef R1
  return x0 ^ x1;
}

__device__ __forceinline__ unsigned long long shfl_down_u64(unsigned long long v, int off) {
  unsigned int lo = (unsigned int)v;
  unsigned int hi = (unsigned int)(v >> 32);
  lo = __shfl_down(lo, off, 64);
  hi = __shfl_down(hi, off, 64);
  return ((unsigned long long)hi << 32) | (unsigned long long)lo;
}

// ---------------------------------------------------------------------------
// Fused kernel: one block per anchor.
// Phase 1 (VALU-bound): masked Gumbel argmax over 8192 columns via threefry.
//   Ordering by (bits>>9) is exactly monotone with the JAX gumbel near the
//   max; ties in (bits>>9) are exact ties in JAX -> first index wins.
//   Packed u64 key ((rank+1)<<13 | 8191-j): max == argmax w/ first-idx tie.
//   Cats packed 4/u32 in LDS: 8 KB -> 8 blocks/CU; 1 conflict-free LDS read
//   per 4 hashes; 4 consecutive j's per thread = 4-way ILP in the hash chain.
// Phase 2 (memory, overlapped across blocks with phase 1's VALU): 3 rows of
//   float4 loads, two squared distances, block reduce, per-anchor store.
// ---------------------------------------------------------------------------
__global__ __launch_bounds__(NT) void fused_kernel(
    const int* __restrict__ cat, const float* __restrict__ eeg,
    const float* __restrict__ text, float* __restrict__ perv,
    float* __restrict__ valv) {
  __shared__ uint32_t scat[N_ANCH / 4];
  __shared__ unsigned long long red[2][4];
  __shared__ float fred[2][4];
  __shared__ int s_pn[2];
  const int t = threadIdx.x;
  const int i = blockIdx.x;

  const int4* cat4 = reinterpret_cast<const int4*>(cat);
  for (int k = t; k < N_ANCH / 4; k += NT) {
    const int4 c = cat4[k];
    scat[k] = (uint32_t)(c.x & 255) | ((uint32_t)(c.y & 255) << 8) |
              ((uint32_t)(c.z & 255) << 16) | ((uint32_t)(c.w & 255) << 24);
  }
  const uint32_t ci = (uint32_t)(cat[i] & 255);
  __syncthreads();

  uint32_t bpR = 0u, bnR = 0u;
  int bpJ = 0, bnJ = 0;
  const uint32_t base = ((uint32_t)i << 13) + ((uint32_t)t << 2);  // i*8192 + t*4

  #pragma unroll 2
  for (int it = 0; it < N_ANCH / (NT * 4); ++it) {  // 8 iterations
    const uint32_t packed = scat[it * NT + t];
    const int j0 = it * (NT * 4) + t * 4;
    #pragma unroll
    for (int u = 0; u < 4; ++u) {
      const uint32_t bits = tf_bits(base + (uint32_t)(it * NT * 4) + (uint32_t)u);
      const uint32_t r = (bits >> 9) + 1u;           // +1 so 0 = "no candidate"
      const uint32_t cj = (packed >> (8 * u)) & 255u;
      const int j = j0 + u;
      const bool eq = (cj == ci);
      const uint32_t rp = (eq && (j != i)) ? r : 0u;
      const uint32_t rn = eq ? 0u : r;
      if (rp > bpR) { bpR = rp; bpJ = j; }  // strict >: earliest j per thread
      if (rn > bnR) { bnR = rn; bnJ = j; }
    }
  }

  unsigned long long kp = ((unsigned long long)bpR << 13) |
                          (unsigned long long)(N_ANCH - 1 - bpJ);
  unsigned long long kn = ((unsigned long long)bnR << 13) |
                          (unsigned long long)(N_ANCH - 1 - bnJ);
  for (int off = 32; off > 0; off >>= 1) {
    const unsigned long long op = shfl_down_u64(kp, off);
    const unsigned long long on = shfl_down_u64(kn, off);
    if (op > kp) kp = op;
    if (on > kn) kn = on;
  }
  const int wave = t >> 6;
  if ((t & 63) == 0) { red[0][wave] = kp; red[1][wave] = kn; }
  __syncthreads();
  if (t == 0) {
    kp = red[0][0]; kn = red[1][0];
    #pragma unroll
    for (int w = 1; w < 4; ++w) {
      if (red[0][w] > kp) kp = red[0][w];
      if (red[1][w] > kn) kn = red[1][w];
    }
    s_pn[0] = (kp >> 13) ? (N_ANCH - 1 - (int)(kp & 8191ull)) : -1;
    s_pn[1] = (kn >> 13) ? (N_ANCH - 1 - (int)(kn & 8191ull)) : -1;
  }
  __syncthreads();

  const int p = s_pn[0];
  const int n = s_pn[1];
  if (p >= 0 && n >= 0) {  // block-uniform branch
    const float4* ea = reinterpret_cast<const float4*>(eeg) + (size_t)i * (DIM / 4);
    const float4* tp = reinterpret_cast<const float4*>(text) + (size_t)p * (DIM / 4);
    const float4* tn = reinterpret_cast<const float4*>(text) + (size_t)n * (DIM / 4);
    const float4 a = ea[t];  // DIM/4 == NT: one float4 per thread
    const float4 b = tp[t];
    const float4 c = tn[t];
    float d0 = a.x - b.x + 1e-6f, d1 = a.y - b.y + 1e-6f;
    float d2 = a.z - b.z + 1e-6f, d3 = a.w - b.w + 1e-6f;
    float sp = d0 * d0 + d1 * d1 + d2 * d2 + d3 * d3;
    d0 = a.x - c.x + 1e-6f; d1 = a.y - c.y + 1e-6f;
    d2 = a.z - c.z + 1e-6f; d3 = a.w - c.w + 1e-6f;
    float sn = d0 * d0 + d1 * d1 + d2 * d2 + d3 * d3;
    for (int off = 32; off > 0; off >>= 1) {
      sp += __shfl_down(sp, off, 64);
      sn += __shfl_down(sn, off, 64);
    }
    if ((t & 63) == 0) { fred[0][wave] = sp; fred[1][wave] = sn; }
    __syncthreads();
    if (t == 0) {
      sp = fred[0][0] + fred[0][1] + fred[0][2] + fred[0][3];
      sn = fred[1][0] + fred[1][1] + fred[1][2] + fred[1][3];
      float per = sqrtf(sp) - sqrtf(sn) + 0.2f;
      perv[i] = per > 0.f ? per : 0.f;
      valv[i] = 1.0f;
    }
  } else if (t == 0) {
    perv[i] = 0.f;
    valv[i] = 0.f;
  }
}

// ---------------------------------------------------------------------------
// Final reduction: one 1024-thread block over 8192 (per, valid) pairs.
// ---------------------------------------------------------------------------
__global__ __launch_bounds__(1024) void reduce_kernel(
    const float* __restrict__ perv, const float* __restrict__ valv,
    float* __restrict__ out) {
  __shared__ float s[2][16];
  const int t = threadIdx.x;
  float sp = 0.f, sv = 0.f;
  for (int k = t; k < N_ANCH; k += 1024) {
    sp += perv[k];
    sv += valv[k];
  }
  for (int off = 32; off > 0; off >>= 1) {
    sp += __shfl_down(sp, off, 64);
    sv += __shfl_down(sv, off, 64);
  }
  const int wave = t >> 6;
  if ((t & 63) == 0) { s[0][wave] = sp; s[1][wave] = sv; }
  __syncthreads();
  if (t == 0) {
    sp = 0.f; sv = 0.f;
    #pragma unroll
    for (int w = 0; w < 16; ++w) { sp += s[0][w]; sv += s[1][w]; }
    out[0] = (sv > 0.f) ? sp / sv : 0.f;
  }
}

extern "C" void kernel_launch(void* const* d_in, const int* in_sizes, int n_in,
                              void* d_out, int out_size, void* d_ws, size_t ws_size,
                              hipStream_t stream) {
  const float* eeg  = (const float*)d_in[0];
  const float* text = (const float*)d_in[1];
  const int*   cat  = (const int*)d_in[2];
  float* out = (float*)d_out;

  float* perv = (float*)d_ws;
  float* valv = perv + N_ANCH;

  hipLaunchKernelGGL(fused_kernel, dim3(N_ANCH), dim3(NT), 0, stream,
                     cat, eeg, text, perv, valv);
  hipLaunchKernelGGL(reduce_kernel, dim3(1), dim3(1024), 0, stream,
                     perv, valv, out);
}

// Round 3
// 148.587 us; speedup vs baseline: 2.7577x; 1.0096x over previous
//
#include <hip/hip_runtime.h>
#include <stdint.h>

#define N_ANCH 8192
#define DIM 1024
#define NT 256

// ---------------------------------------------------------------------------
// rotl(x, r) == rotr(x, 32-r) == v_alignbit_b32 d, x, x, (32-r)  (1 VALU op)
// ---------------------------------------------------------------------------
#define ROTX(dst, src, simm) \
  asm("v_alignbit_b32 %0, %1, %1, " simm : "=v"(dst) : "v"(src))

// Threefry-2x32, key = (0, 42), counts = (0, lo). Returns o0 ^ o1 (JAX
// partitionable combine). Bit-exact vs JAX (validated R1/R2: absmax 0.0).
// Caller passes lo + 42 (the ks1 injection on x1 pre-folded).
__device__ __forceinline__ uint32_t tf_bits(uint32_t lo42) {
  const uint32_t ks1 = 42u;
  const uint32_t ks2 = 42u ^ 0x1BD11BDAu;
  uint32_t x0, x1, t;
  // Round 1 with x0_init = 0 folded: x0 = x1_init; x1 = rotl(x1_init,13)^x0.
  x0 = lo42;
  ROTX(t, lo42, "19"); x1 = t ^ x0;
  x0 += x1; ROTX(t, x1, "17"); x1 = t ^ x0;   // rotl 15
  x0 += x1; ROTX(t, x1, "6");  x1 = t ^ x0;   // rotl 26
  x0 += x1; ROTX(t, x1, "26"); x1 = t ^ x0;   // rotl 6
  x0 += ks1; x1 += ks2 + 1u;
  x0 += x1; ROTX(t, x1, "15"); x1 = t ^ x0;   // rotl 17
  x0 += x1; ROTX(t, x1, "3");  x1 = t ^ x0;   // rotl 29
  x0 += x1; ROTX(t, x1, "16"); x1 = t ^ x0;   // rotl 16
  x0 += x1; ROTX(t, x1, "8");  x1 = t ^ x0;   // rotl 24
  x0 += ks2; x1 += 2u;                         // ks0 = 0
  x0 += x1; ROTX(t, x1, "19"); x1 = t ^ x0;   // rotl 13
  x0 += x1; ROTX(t, x1, "17"); x1 = t ^ x0;   // rotl 15
  x0 += x1; ROTX(t, x1, "6");  x1 = t ^ x0;   // rotl 26
  x0 += x1; ROTX(t, x1, "26"); x1 = t ^ x0;   // rotl 6
  x0 += 0u; x1 += ks1 + 3u;
  x0 += x1; ROTX(t, x1, "15"); x1 = t ^ x0;   // rotl 17
  x0 += x1; ROTX(t, x1, "3");  x1 = t ^ x0;   // rotl 29
  x0 += x1; ROTX(t, x1, "16"); x1 = t ^ x0;   // rotl 16
  x0 += x1; ROTX(t, x1, "8");  x1 = t ^ x0;   // rotl 24
  x0 += ks1; x1 += ks2 + 4u;
  x0 += x1; ROTX(t, x1, "19"); x1 = t ^ x0;   // rotl 13
  x0 += x1; ROTX(t, x1, "17"); x1 = t ^ x0;   // rotl 15
  x0 += x1; ROTX(t, x1, "6");  x1 = t ^ x0;   // rotl 26
  x0 += x1; ROTX(t, x1, "26"); x1 = t ^ x0;   // rotl 6
  x0 += ks2; x1 += 5u;                         // ks0 = 0
  return x0 ^ x1;
}

__device__ __forceinline__ unsigned long long shfl_down_u64(unsigned long long v, int off) {
  unsigned int lo = (unsigned int)v;
  unsigned int hi = (unsigned int)(v >> 32);
  lo = __shfl_down(lo, off, 64);
  hi = __shfl_down(hi, off, 64);
  return ((unsigned long long)hi << 32) | (unsigned long long)lo;
}

// ---------------------------------------------------------------------------
// Fused kernel: one block per anchor i.
// Phase 1 (VALU): masked Gumbel argmax over 8192 cols. Thread t owns
//   j = it*1024 + t*4 + u (it=0..7, u=0..3). Per-(u) tracker holds
//   key = ((bits>>9)<<3) | (7-it): u32 max == argmax rank w/ earliest-it
//   tie-break; u/thread tie-break handled in the exact u64 combine
//   ((rank<<13)|(8191-j)). key==0 ambiguity (rank0@it7 vs empty) and
//   phantom winners are closed by post-validation against LDS cats.
// Phase 2 (memory, overlaps phase-1 VALU across blocks): 3x float4 row
//   loads, two squared distances, block reduce, per-anchor store.
// ---------------------------------------------------------------------------
__global__ __launch_bounds__(NT) void fused_kernel(
    const int* __restrict__ cat, const float* __restrict__ eeg,
    const float* __restrict__ text, float* __restrict__ perv,
    float* __restrict__ valv) {
  __shared__ uint32_t scat[N_ANCH / 4];
  __shared__ unsigned long long red[2][4];
  __shared__ float fred[2][4];
  __shared__ int s_pn[2];
  const int t = threadIdx.x;
  const int i = blockIdx.x;

  const int4* cat4 = reinterpret_cast<const int4*>(cat);
  for (int k = t; k < N_ANCH / 4; k += NT) {
    const int4 c = cat4[k];
    scat[k] = (uint32_t)(c.x & 255) | ((uint32_t)(c.y & 255) << 8) |
              ((uint32_t)(c.z & 255) << 16) | ((uint32_t)(c.w & 255) << 24);
  }
  __syncthreads();

  const uint32_t ci = (scat[i >> 2] >> ((i & 3) * 8)) & 255u;

  // Prefetch this thread's 8 packed cat words into registers (no LDS in loop).
  uint32_t cw[8];
  #pragma unroll
  for (int it = 0; it < 8; ++it) cw[it] = scat[it * NT + t];

  // self_it[u]: the iteration at which j == i for this thread's slot u (or 255).
  const int ilow = i & 1023, ihigh = i >> 10, t4 = t << 2;
  int s_it[4];
  #pragma unroll
  for (int u = 0; u < 4; ++u) s_it[u] = (t4 + u == ilow) ? ihigh : 255;

  uint32_t kp[4] = {0u, 0u, 0u, 0u};
  uint32_t kn[4] = {0u, 0u, 0u, 0u};
  const uint32_t base42 = ((uint32_t)i << 13) + (uint32_t)t4 + 42u;

  #pragma unroll 2
  for (int it = 0; it < 8; ++it) {
    const uint32_t packed = cw[it];
    #pragma unroll
    for (int u = 0; u < 4; ++u) {
      const uint32_t bits = tf_bits(base42 + (uint32_t)(it * 1024 + u));
      const uint32_t keyb = ((bits >> 6) & 0xFFFFFFF8u) | (uint32_t)(7 - it);
      const uint32_t cj = (packed >> (8 * u)) & 255u;
      const bool eq = (cj == ci);
      const uint32_t kpc = (eq && (it != s_it[u])) ? keyb : 0u;
      const uint32_t knc = eq ? 0u : keyb;
      kp[u] = kp[u] >= kpc ? kp[u] : kpc;
      kn[u] = kn[u] >= knc ? kn[u] : knc;
    }
  }

  // Exact per-thread combine across u-slots: (rank, smallest j) wins.
  unsigned long long bp = 0ull, bn = 0ull;
  #pragma unroll
  for (int u = 0; u < 4; ++u) {
    if (kp[u]) {
      const uint32_t r = kp[u] >> 3;
      const int itw = 7 - (int)(kp[u] & 7u);
      const int j = itw * 1024 + t4 + u;
      const unsigned long long cand =
          ((unsigned long long)r << 13) | (unsigned long long)(8191 - j);
      if (cand > bp) bp = cand;
    }
    if (kn[u]) {
      const uint32_t r = kn[u] >> 3;
      const int itw = 7 - (int)(kn[u] & 7u);
      const int j = itw * 1024 + t4 + u;
      const unsigned long long cand =
          ((unsigned long long)r << 13) | (unsigned long long)(8191 - j);
      if (cand > bn) bn = cand;
    }
  }

  for (int off = 32; off > 0; off >>= 1) {
    const unsigned long long op = shfl_down_u64(bp, off);
    const unsigned long long on = shfl_down_u64(bn, off);
    if (op > bp) bp = op;
    if (on > bn) bn = on;
  }
  const int wave = t >> 6;
  if ((t & 63) == 0) { red[0][wave] = bp; red[1][wave] = bn; }
  __syncthreads();
  if (t == 0) {
    bp = red[0][0]; bn = red[1][0];
    #pragma unroll
    for (int w = 1; w < 4; ++w) {
      if (red[0][w] > bp) bp = red[0][w];
      if (red[1][w] > bn) bn = red[1][w];
    }
    int p = bp ? (8191 - (int)(bp & 8191ull)) : -1;
    int n = bn ? (8191 - (int)(bn & 8191ull)) : -1;
    // Exact post-validation (closes key==0 ambiguity & singleton categories).
    if (p >= 0) {
      const uint32_t cp = (scat[p >> 2] >> ((p & 3) * 8)) & 255u;
      if (cp != ci || p == i) p = -1;
    }
    if (n >= 0) {
      const uint32_t cn = (scat[n >> 2] >> ((n & 3) * 8)) & 255u;
      if (cn == ci) n = -1;
    }
    s_pn[0] = p;
    s_pn[1] = n;
  }
  __syncthreads();

  const int p = s_pn[0];
  const int n = s_pn[1];
  if (p >= 0 && n >= 0) {  // block-uniform branch
    const float4* ea = reinterpret_cast<const float4*>(eeg) + (size_t)i * (DIM / 4);
    const float4* tp = reinterpret_cast<const float4*>(text) + (size_t)p * (DIM / 4);
    const float4* tn = reinterpret_cast<const float4*>(text) + (size_t)n * (DIM / 4);
    const float4 a = ea[t];  // DIM/4 == NT: one float4 per thread
    const float4 b = tp[t];
    const float4 c = tn[t];
    float d0 = a.x - b.x + 1e-6f, d1 = a.y - b.y + 1e-6f;
    float d2 = a.z - b.z + 1e-6f, d3 = a.w - b.w + 1e-6f;
    float sp = d0 * d0 + d1 * d1 + d2 * d2 + d3 * d3;
    d0 = a.x - c.x + 1e-6f; d1 = a.y - c.y + 1e-6f;
    d2 = a.z - c.z + 1e-6f; d3 = a.w - c.w + 1e-6f;
    float sn = d0 * d0 + d1 * d1 + d2 * d2 + d3 * d3;
    for (int off = 32; off > 0; off >>= 1) {
      sp += __shfl_down(sp, off, 64);
      sn += __shfl_down(sn, off, 64);
    }
    if ((t & 63) == 0) { fred[0][wave] = sp; fred[1][wave] = sn; }
    __syncthreads();
    if (t == 0) {
      sp = fred[0][0] + fred[0][1] + fred[0][2] + fred[0][3];
      sn = fred[1][0] + fred[1][1] + fred[1][2] + fred[1][3];
      float per = sqrtf(sp) - sqrtf(sn) + 0.2f;
      perv[i] = per > 0.f ? per : 0.f;
      valv[i] = 1.0f;
    }
  } else if (t == 0) {
    perv[i] = 0.f;
    valv[i] = 0.f;
  }
}

// ---------------------------------------------------------------------------
// Final reduction: one 1024-thread block over 8192 (per, valid) pairs.
// ---------------------------------------------------------------------------
__global__ __launch_bounds__(1024) void reduce_kernel(
    const float* __restrict__ perv, const float* __restrict__ valv,
    float* __restrict__ out) {
  __shared__ float s[2][16];
  const int t = threadIdx.x;
  float sp = 0.f, sv = 0.f;
  for (int k = t; k < N_ANCH; k += 1024) {
    sp += perv[k];
    sv += valv[k];
  }
  for (int off = 32; off > 0; off >>= 1) {
    sp += __shfl_down(sp, off, 64);
    sv += __shfl_down(sv, off, 64);
  }
  const int wave = t >> 6;
  if ((t & 63) == 0) { s[0][wave] = sp; s[1][wave] = sv; }
  __syncthreads();
  if (t == 0) {
    sp = 0.f; sv = 0.f;
    #pragma unroll
    for (int w = 0; w < 16; ++w) { sp += s[0][w]; sv += s[1][w]; }
    out[0] = (sv > 0.f) ? sp / sv : 0.f;
  }
}

extern "C" void kernel_launch(void* const* d_in, const int* in_sizes, int n_in,
                              void* d_out, int out_size, void* d_ws, size_t ws_size,
                              hipStream_t stream) {
  const float* eeg  = (const float*)d_in[0];
  const float* text = (const float*)d_in[1];
  const int*   cat  = (const int*)d_in[2];
  float* out = (float*)d_out;

  float* perv = (float*)d_ws;
  float* valv = perv + N_ANCH;

  hipLaunchKernelGGL(fused_kernel, dim3(N_ANCH), dim3(NT), 0, stream,
                     cat, eeg, text, perv, valv);
  hipLaunchKernelGGL(reduce_kernel, dim3(1), dim3(1024), 0, stream,
                     perv, valv, out);
}

// Round 4
// 139.982 us; speedup vs baseline: 2.9272x; 1.0615x over previous
//
#include <hip/hip_runtime.h>
#include <stdint.h>

#define N_ANCH 8192
#define DIM 1024
#define NT 256

// rotl(x, r) == rotr(x, 32-r) via v_alignbit_b32 (1 VALU op).
__device__ __forceinline__ uint32_t rotr_ab(uint32_t x, uint32_t sh) {
  return __builtin_amdgcn_alignbit(x, x, sh);
}

// ---------------------------------------------------------------------------
// Four interleaved Threefry-2x32 hashes, key = (0,42), counts = (0, lo+u),
// u = 0..3. Returns o0 ^ o1 per chain (JAX partitionable combine; bit-exact
// vs JAX, validated R1-R3: absmax 0.0). Explicit 4-way interleave forces the
// register allocator to keep 4 independent dep-chains live (R3's VGPR=24
// showed it serialized them, leaving issue slots uncovered).
// ---------------------------------------------------------------------------
__device__ __forceinline__ void tf4(uint32_t lo, uint32_t bits[4]) {
  const uint32_t ks1 = 42u;
  const uint32_t ks2 = 42u ^ 0x1BD11BDAu;
  uint32_t x0[4], x1[4];
  // Round 1 folded: x0_new = lo+42+u ; x1_new = rotl(x0_new,13) ^ x0_new.
#define TF_INIT(u) { const uint32_t l = lo + (u); x0[u] = l; \
                     x1[u] = rotr_ab(l, 19) ^ l; }
  TF_INIT(0) TF_INIT(1) TF_INIT(2) TF_INIT(3)
#undef TF_INIT
#define RND(sh) \
  x0[0] += x1[0]; x1[0] = rotr_ab(x1[0], sh) ^ x0[0]; \
  x0[1] += x1[1]; x1[1] = rotr_ab(x1[1], sh) ^ x0[1]; \
  x0[2] += x1[2]; x1[2] = rotr_ab(x1[2], sh) ^ x0[2]; \
  x0[3] += x1[3]; x1[3] = rotr_ab(x1[3], sh) ^ x0[3];
#define INJ(a0, a1) \
  x0[0] += (a0); x1[0] += (a1); x0[1] += (a0); x1[1] += (a1); \
  x0[2] += (a0); x1[2] += (a1); x0[3] += (a0); x1[3] += (a1);
  RND(17) RND(6) RND(26)            // rotl 15, 26, 6 (round 1 folded above)
  INJ(ks1, ks2 + 1u)
  RND(15) RND(3) RND(16) RND(8)     // rotl 17, 29, 16, 24
  INJ(ks2, 2u)
  RND(19) RND(17) RND(6) RND(26)    // rotl 13, 15, 26, 6
  x1[0] += ks1 + 3u; x1[1] += ks1 + 3u; x1[2] += ks1 + 3u; x1[3] += ks1 + 3u;
  RND(15) RND(3) RND(16) RND(8)     // rotl 17, 29, 16, 24
  INJ(ks1, ks2 + 4u)
  RND(19) RND(17) RND(6) RND(26)    // rotl 13, 15, 26, 6
  INJ(ks2, 5u)
#undef RND
#undef INJ
  bits[0] = x0[0] ^ x1[0]; bits[1] = x0[1] ^ x1[1];
  bits[2] = x0[2] ^ x1[2]; bits[3] = x0[3] ^ x1[3];
}

__device__ __forceinline__ unsigned long long shfl_down_u64(unsigned long long v, int off) {
  unsigned int lo = (unsigned int)v;
  unsigned int hi = (unsigned int)(v >> 32);
  lo = __shfl_down(lo, off, 64);
  hi = __shfl_down(hi, off, 64);
  return ((unsigned long long)hi << 32) | (unsigned long long)lo;
}

// ---------------------------------------------------------------------------
// Fused kernel: one block per anchor i. Thread t owns j = it*1024 + t*4 + u.
// Per-side u32 tracker key = (bits>>9)<<5 | ((7-it)<<2) | (3-u): u32 max ==
// (rank, smallest-j-within-thread) argmax; cross-thread j tie-break exact in
// the u64 combine ((rank<<13)|(8191-j)). key==0 corner + phantom winners
// closed by post-validation against LDS cats. Distances fused as phase 2.
// ---------------------------------------------------------------------------
__global__ __launch_bounds__(NT, 8) void fused_kernel(
    const int* __restrict__ cat, const float* __restrict__ eeg,
    const float* __restrict__ text, float* __restrict__ perv,
    float* __restrict__ valv) {
  __shared__ uint32_t scat[N_ANCH / 4];
  __shared__ unsigned long long red[2][4];
  __shared__ float fred[2][4];
  __shared__ int s_pn[2];
  const int t = threadIdx.x;
  const int i = blockIdx.x;

  const int4* cat4 = reinterpret_cast<const int4*>(cat);
  for (int k = t; k < N_ANCH / 4; k += NT) {
    const int4 c = cat4[k];
    scat[k] = (uint32_t)(c.x & 255) | ((uint32_t)(c.y & 255) << 8) |
              ((uint32_t)(c.z & 255) << 16) | ((uint32_t)(c.w & 255) << 24);
  }
  __syncthreads();

  const uint32_t ci = (scat[i >> 2] >> ((i & 3) * 8)) & 255u;

  // Prefetch this thread's 8 packed cat words into registers.
  uint32_t cw[8];
  #pragma unroll
  for (int it = 0; it < 8; ++it) cw[it] = scat[it * NT + t];

  const int t4 = t << 2;
  // selfcode = it*4+u of the j==i slot if this thread owns it, else 255.
  const uint32_t selfcode =
      (((i & 1023) >> 2) == t) ? ((uint32_t)((i >> 10) << 2) | (uint32_t)(i & 3))
                               : 255u;

  uint32_t kp = 0u, kn = 0u;
  const uint32_t base42 = ((uint32_t)i << 13) + (uint32_t)t4 + 42u;

#define DO_U(it, u) { \
    const uint32_t keyb = ((bits[u] >> 4) & 0xFFFFFFE0u) | \
                          (uint32_t)((((7 - (it)) << 2) | (3 - (u)))); \
    const uint32_t cj = (packed >> (8 * (u))) & 255u; \
    const bool eq = (cj == ci); \
    const bool ns = ((uint32_t)((it) * 4 + (u)) != selfcode); \
    const uint32_t kpc = (eq && ns) ? keyb : 0u; \
    const uint32_t knc = eq ? 0u : keyb; \
    kp = kp >= kpc ? kp : kpc; \
    kn = kn >= knc ? kn : knc; }
#define DO_IT(it) { \
    const uint32_t packed = cw[it]; \
    uint32_t bits[4]; \
    tf4(base42 + (uint32_t)((it) * 1024), bits); \
    DO_U(it, 0) DO_U(it, 1) DO_U(it, 2) DO_U(it, 3) }

  DO_IT(0) DO_IT(1) DO_IT(2) DO_IT(3)
  DO_IT(4) DO_IT(5) DO_IT(6) DO_IT(7)
#undef DO_IT
#undef DO_U

  // Exact u64 pack: (rank << 13) | (8191 - j).
  unsigned long long bp = 0ull, bn = 0ull;
  if (kp) {
    const int emb = (int)(kp & 31u);
    const int j = (7 - (emb >> 2)) * 1024 + t4 + (3 - (emb & 3));
    bp = ((unsigned long long)(kp >> 5) << 13) | (unsigned long long)(8191 - j);
  }
  if (kn) {
    const int emb = (int)(kn & 31u);
    const int j = (7 - (emb >> 2)) * 1024 + t4 + (3 - (emb & 3));
    bn = ((unsigned long long)(kn >> 5) << 13) | (unsigned long long)(8191 - j);
  }

  for (int off = 32; off > 0; off >>= 1) {
    const unsigned long long op = shfl_down_u64(bp, off);
    const unsigned long long on = shfl_down_u64(bn, off);
    if (op > bp) bp = op;
    if (on > bn) bn = on;
  }
  const int wave = t >> 6;
  if ((t & 63) == 0) { red[0][wave] = bp; red[1][wave] = bn; }
  __syncthreads();
  if (t == 0) {
    bp = red[0][0]; bn = red[1][0];
    #pragma unroll
    for (int w = 1; w < 4; ++w) {
      if (red[0][w] > bp) bp = red[0][w];
      if (red[1][w] > bn) bn = red[1][w];
    }
    int p = bp ? (8191 - (int)(bp & 8191ull)) : -1;
    int n = bn ? (8191 - (int)(bn & 8191ull)) : -1;
    // Exact post-validation (closes key==0 corner & singleton categories).
    if (p >= 0) {
      const uint32_t cp = (scat[p >> 2] >> ((p & 3) * 8)) & 255u;
      if (cp != ci || p == i) p = -1;
    }
    if (n >= 0) {
      const uint32_t cn = (scat[n >> 2] >> ((n & 3) * 8)) & 255u;
      if (cn == ci) n = -1;
    }
    s_pn[0] = p;
    s_pn[1] = n;
  }
  __syncthreads();

  const int p = s_pn[0];
  const int n = s_pn[1];
  if (p >= 0 && n >= 0) {  // block-uniform branch
    const float4* ea = reinterpret_cast<const float4*>(eeg) + (size_t)i * (DIM / 4);
    const float4* tp = reinterpret_cast<const float4*>(text) + (size_t)p * (DIM / 4);
    const float4* tn = reinterpret_cast<const float4*>(text) + (size_t)n * (DIM / 4);
    const float4 a = ea[t];  // DIM/4 == NT: one float4 per thread
    const float4 b = tp[t];
    const float4 c = tn[t];
    float d0 = a.x - b.x + 1e-6f, d1 = a.y - b.y + 1e-6f;
    float d2 = a.z - b.z + 1e-6f, d3 = a.w - b.w + 1e-6f;
    float sp = d0 * d0 + d1 * d1 + d2 * d2 + d3 * d3;
    d0 = a.x - c.x + 1e-6f; d1 = a.y - c.y + 1e-6f;
    d2 = a.z - c.z + 1e-6f; d3 = a.w - c.w + 1e-6f;
    float sn = d0 * d0 + d1 * d1 + d2 * d2 + d3 * d3;
    for (int off = 32; off > 0; off >>= 1) {
      sp += __shfl_down(sp, off, 64);
      sn += __shfl_down(sn, off, 64);
    }
    if ((t & 63) == 0) { fred[0][wave] = sp; fred[1][wave] = sn; }
    __syncthreads();
    if (t == 0) {
      sp = fred[0][0] + fred[0][1] + fred[0][2] + fred[0][3];
      sn = fred[1][0] + fred[1][1] + fred[1][2] + fred[1][3];
      float per = sqrtf(sp) - sqrtf(sn) + 0.2f;
      perv[i] = per > 0.f ? per : 0.f;
      valv[i] = 1.0f;
    }
  } else if (t == 0) {
    perv[i] = 0.f;
    valv[i] = 0.f;
  }
}

// ---------------------------------------------------------------------------
// Final reduction: one 1024-thread block over 8192 (per, valid) pairs.
// ---------------------------------------------------------------------------
__global__ __launch_bounds__(1024) void reduce_kernel(
    const float* __restrict__ perv, const float* __restrict__ valv,
    float* __restrict__ out) {
  __shared__ float s[2][16];
  const int t = threadIdx.x;
  float sp = 0.f, sv = 0.f;
  for (int k = t; k < N_ANCH; k += 1024) {
    sp += perv[k];
    sv += valv[k];
  }
  for (int off = 32; off > 0; off >>= 1) {
    sp += __shfl_down(sp, off, 64);
    sv += __shfl_down(sv, off, 64);
  }
  const int wave = t >> 6;
  if ((t & 63) == 0) { s[0][wave] = sp; s[1][wave] = sv; }
  __syncthreads();
  if (t == 0) {
    sp = 0.f; sv = 0.f;
    #pragma unroll
    for (int w = 0; w < 16; ++w) { sp += s[0][w]; sv += s[1][w]; }
    out[0] = (sv > 0.f) ? sp / sv : 0.f;
  }
}

extern "C" void kernel_launch(void* const* d_in, const int* in_sizes, int n_in,
                              void* d_out, int out_size, void* d_ws, size_t ws_size,
                              hipStream_t stream) {
  const float* eeg  = (const float*)d_in[0];
  const float* text = (const float*)d_in[1];
  const int*   cat  = (const int*)d_in[2];
  float* out = (float*)d_out;

  float* perv = (float*)d_ws;
  float* valv = perv + N_ANCH;

  hipLaunchKernelGGL(fused_kernel, dim3(N_ANCH), dim3(NT), 0, stream,
                     cat, eeg, text, perv, valv);
  hipLaunchKernelGGL(reduce_kernel, dim3(1), dim3(1024), 0, stream,
                     perv, valv, out);
}